// Round 2
// baseline (4391.068 us; speedup 1.0000x reference)
//
#include <hip/hip_runtime.h>
#include <stdint.h>

#define BB 64
#define TT 256
#define VV 32000
#define DD 512
#define HH 1024
#define FH 4096

// Padded U row stride: 2048 data bytes + 16 pad = 2064 (4-bank shift per row)
#define UROW 2064
#define UBLK (64 * UROW)   // 132096 bytes per WG

typedef float f32x4 __attribute__((ext_vector_type(4)));
typedef __bf16 bf16x8 __attribute__((ext_vector_type(8)));

typedef __attribute__((address_space(1))) void void_g;
typedef __attribute__((address_space(3))) void void_l;

static __device__ __forceinline__ void gload_lds16(const void* g, void* l) {
  __builtin_amdgcn_global_load_lds((const void_g*)g, (void_l*)l, 16, 0, 0);
}

static __device__ __forceinline__ unsigned short f2bf(float f) {
  union { float f; unsigned u; } x; x.f = f;
  unsigned r = x.u + 0x7FFFu + ((x.u >> 16) & 1u);
  return (unsigned short)(r >> 16);
}
static __device__ __forceinline__ float bf2f(unsigned short s) {
  union { unsigned u; float f; } x; x.u = ((unsigned)s) << 16;
  return x.f;
}
static __device__ __forceinline__ bf16x8 as_bf16x8(uint4 v) {
  union { uint4 u; bf16x8 b; } x; x.u = v; return x.b;
}
static __device__ __forceinline__ float sigm(float x) {
  return 1.f / (1.f + __expf(-x));
}
static __device__ __forceinline__ float tanh_f(float x) {
  x = fminf(15.f, fmaxf(-15.f, x));
  float e = __expf(2.f * x);
  return (e - 1.f) / (e + 1.f);
}
static __device__ __forceinline__ float get_bf_u2(uint2 v, int u) {
  unsigned r = (u < 2) ? v.x : v.y;
  return bf2f((unsigned short)((u & 1) ? (r >> 16) : (r & 0xFFFFu)));
}

// ---------------- prep kernels ----------------

__global__ void k_cast_emb(const float* __restrict__ src, unsigned short* __restrict__ dst) {
  size_t i = ((size_t)blockIdx.x * 256 + threadIdx.x) * 8;
  float4 a = *(const float4*)(src + i);
  float4 b = *(const float4*)(src + i + 4);
  uint4 o;
  o.x = (unsigned)f2bf(a.x) | ((unsigned)f2bf(a.y) << 16);
  o.y = (unsigned)f2bf(a.z) | ((unsigned)f2bf(a.w) << 16);
  o.z = (unsigned)f2bf(b.x) | ((unsigned)f2bf(b.y) << 16);
  o.w = (unsigned)f2bf(b.z) | ((unsigned)f2bf(b.w) << 16);
  *(uint4*)(dst + i) = o;
}

// W_t[n'][k] bf16 (transposed, column-permuted), b_perm[n'] f32.
// n' = w*64 + g*16 + jj  <->  n = g*1024 + w*16 + jj
__global__ void k_prep_w(const float* __restrict__ Wsrc, const float* __restrict__ bsrc,
                         unsigned short* __restrict__ Wt, float* __restrict__ bperm) {
  int np = blockIdx.x;
  int w = np >> 6, r = np & 63, g = r >> 4, jj = r & 15;
  int n = g * 1024 + w * 16 + jj;
  int k0 = threadIdx.x * 4;
  unsigned short q0 = f2bf(Wsrc[(size_t)(k0 + 0) * FH + n]);
  unsigned short q1 = f2bf(Wsrc[(size_t)(k0 + 1) * FH + n]);
  unsigned short q2 = f2bf(Wsrc[(size_t)(k0 + 2) * FH + n]);
  unsigned short q3 = f2bf(Wsrc[(size_t)(k0 + 3) * FH + n]);
  uint2 o;
  o.x = (unsigned)q0 | ((unsigned)q1 << 16);
  o.y = (unsigned)q2 | ((unsigned)q3 << 16);
  *(uint2*)((char*)Wt + (size_t)np * 1024 + (size_t)k0 * 2) = o;
  if (threadIdx.x == 0) bperm[np] = bsrc[n];
}

// U_prep: per WG w, padded-linear LDS image: row j (64 rows) at j*UROW,
// 2048 bytes of bf16 U[n(j,w)][k] + 16 pad bytes (zeroed).
__global__ void k_prep_u(const float* __restrict__ Usrc, unsigned short* __restrict__ Uprep) {
  int bid = blockIdx.x;            // 0..4095 = w*64 + j
  int j = bid & 63;
  int w = bid >> 6;
  int g = j >> 4, jj = j & 15;
  int n = g * 1024 + w * 16 + jj;
  int k0 = threadIdx.x * 8;
  unsigned p[4];
  #pragma unroll
  for (int h = 0; h < 4; ++h) {
    unsigned short e0 = f2bf(Usrc[(size_t)(k0 + 2 * h) * FH + n]);
    unsigned short e1 = f2bf(Usrc[(size_t)(k0 + 2 * h + 1) * FH + n]);
    p[h] = (unsigned)e0 | ((unsigned)e1 << 16);
  }
  uint4 o; o.x = p[0]; o.y = p[1]; o.z = p[2]; o.w = p[3];
  char* dst = (char*)Uprep + (size_t)w * UBLK + (size_t)j * UROW;
  *(uint4*)(dst + threadIdx.x * 16) = o;
  if (threadIdx.x == 0) { uint4 z = {0, 0, 0, 0}; *(uint4*)(dst + 2048) = z; }
}

__global__ void k_mask(const int* __restrict__ tok, unsigned long long* __restrict__ mask64) {
  int t = threadIdx.x;
  unsigned long long m = 0;
  for (int b = 0; b < BB; ++b)
    m |= (unsigned long long)(tok[b * TT + t] != 0) << b;
  mask64[t] = m;
}

// ---------------- xW GEMM (gather fused) ----------------
// xw[row=(b*T+t)][n'] bf16 = emb[tok[row]] @ W (+b), 128x128 tile, K=512

__launch_bounds__(256)
__global__ void k_gemm_xw(const int* __restrict__ tok, const unsigned short* __restrict__ embb,
                          const unsigned short* __restrict__ Wt, const float* __restrict__ bperm,
                          unsigned short* __restrict__ xw) {
  __shared__ char As[16384];
  __shared__ char Bs[16384];
  __shared__ int toks[128];
  int tid = threadIdx.x, lane = tid & 63, wid = tid >> 6;
  int bm = blockIdx.x >> 5, bn = blockIdx.x & 31;
  if (tid < 128) toks[tid] = tok[bm * 128 + tid];
  int wm = wid >> 1, wn = wid & 1;
  f32x4 vz = {0.f, 0.f, 0.f, 0.f};
  f32x4 acc[4][4];
  #pragma unroll
  for (int i = 0; i < 4; ++i)
    #pragma unroll
    for (int j = 0; j < 4; ++j) acc[i][j] = vz;

  int kls = (lane >> 4) * 16;
  for (int ks = 0; ks < 8; ++ks) {
    __syncthreads();
    #pragma unroll
    for (int c = 0; c < 4; ++c) {
      int o = wid * 4096 + c * 1024 + lane * 16;
      int m = o >> 7, kl = o & 127;
      const char* ga = (const char*)embb + (size_t)toks[m] * 1024 + ks * 128 + (kl ^ ((m & 7) << 4));
      gload_lds16(ga, As + o);
      const char* gb = (const char*)Wt + (size_t)(bn * 128 + m) * 1024 + ks * 128 + (kl ^ ((m & 7) << 4));
      gload_lds16(gb, Bs + o);
    }
    asm volatile("s_waitcnt vmcnt(0)" ::: "memory");
    __syncthreads();
    #pragma unroll
    for (int tk = 0; tk < 2; ++tk) {
      bf16x8 af[4], bf[4];
      int kb = tk * 64 + kls;
      #pragma unroll
      for (int mt = 0; mt < 4; ++mt) {
        int m = wm * 64 + mt * 16 + (lane & 15);
        af[mt] = *(const bf16x8*)(As + m * 128 + (kb ^ ((m & 7) << 4)));
      }
      #pragma unroll
      for (int nt = 0; nt < 4; ++nt) {
        int n = wn * 64 + nt * 16 + (lane & 15);
        bf[nt] = *(const bf16x8*)(Bs + n * 128 + (kb ^ ((n & 7) << 4)));
      }
      #pragma unroll
      for (int mt = 0; mt < 4; ++mt)
        #pragma unroll
        for (int nt = 0; nt < 4; ++nt)
          acc[mt][nt] = __builtin_amdgcn_mfma_f32_16x16x32_bf16(af[mt], bf[nt], acc[mt][nt], 0, 0, 0);
    }
  }
  #pragma unroll
  for (int nt = 0; nt < 4; ++nt) {
    int col = bn * 128 + wn * 64 + nt * 16 + (lane & 15);
    float bias = bperm[col];
    #pragma unroll
    for (int mt = 0; mt < 4; ++mt) {
      #pragma unroll
      for (int r = 0; r < 4; ++r) {
        int row = bm * 128 + wm * 64 + mt * 16 + (lane >> 4) * 4 + r;
        xw[(size_t)row * FH + col] = f2bf(acc[mt][nt][r] + bias);
      }
    }
  }
}

// ---------------- persistent LSTM scan ----------------
// 64 WGs, WG w owns h cols [16w,16w+16) (z cols j=g*16+jj of n'=w*64+j).
// U slice resident in LDS (padded rows, stride UROW); h broadcast via per-step
// global buffers (monotonic addresses) + device-scope flags.

#define LSTM_LDS (UBLK + 16640 + 4096 + 4096)

__launch_bounds__(256, 1)
__global__ void k_lstm(const unsigned short* __restrict__ Uprep, const unsigned short* __restrict__ xw,
                       const unsigned long long* __restrict__ mask64,
                       unsigned short* __restrict__ hseq, unsigned* __restrict__ flags,
                       float* __restrict__ hfin) {
  extern __shared__ char smem[];
  char* Us = smem;
  float* zl = (float*)(smem + UBLK);                 // [64][65] f32
  float* cb = (float*)(smem + UBLK + 16640);         // [64][16] f32
  float* ho = (float*)(smem + UBLK + 16640 + 4096);  // [64][16] f32
  int tid = threadIdx.x, lane = tid & 63, wid = tid >> 6;
  int w = blockIdx.x;

  {
    const char* src = (const char*)Uprep + (size_t)w * UBLK;
    #pragma unroll
    for (int c = 0; c < 32; ++c) {
      int o = c * 4096 + tid * 16;
      gload_lds16(src + o, Us + o);
    }
    if (wid == 0) {  // tail: 1024 bytes
      int o = 131072 + lane * 16;
      gload_lds16(src + o, Us + o);
    }
  }
  for (int i = tid; i < 1024; i += 256) { cb[i] = 0.f; ho[i] = 0.f; }
  asm volatile("s_waitcnt vmcnt(0)" ::: "memory");
  __syncthreads();

  int m2 = wid >> 1, n2 = wid & 1;
  int kls = (lane >> 4) * 16;
  int j0 = n2 * 32 + (lane & 15);
  int bo0 = j0 * UROW + kls;
  int bo1 = bo0 + 16 * UROW;
  int ub = tid >> 2, uq = tid & 3;

  for (int t = 0; t < TT; ++t) {
    uint2 xg[4];
    {
      const char* xp = (const char*)xw + (((size_t)ub * TT + t) * FH + w * 64) * 2;
      #pragma unroll
      for (int g = 0; g < 4; ++g) xg[g] = *(const uint2*)(xp + (g * 16 + uq * 4) * 2);
    }
    unsigned long long mb = mask64[t];
    f32x4 a00 = {0.f,0.f,0.f,0.f}, a01 = {0.f,0.f,0.f,0.f};
    f32x4 a10 = {0.f,0.f,0.f,0.f}, a11 = {0.f,0.f,0.f,0.f};

    if (t > 0) {
      if (wid == 0) {
        unsigned* fl = flags + (size_t)(t - 1) * 64;
        for (;;) {
          unsigned v = __hip_atomic_load(fl + lane, __ATOMIC_RELAXED, __HIP_MEMORY_SCOPE_AGENT);
          if (__all(v != 0)) break;
          __builtin_amdgcn_s_sleep(2);
        }
        __builtin_amdgcn_fence(__ATOMIC_ACQUIRE, "agent");
      }
      __syncthreads();
      const char* hp = (const char*)hseq + (size_t)(t - 1) * 131072;
      const char* ap0 = hp + (m2 * 32 + (lane & 15)) * 2048 + kls;
      const char* ap1 = ap0 + 16 * 2048;
      #pragma unroll 8
      for (int tk = 0; tk < 32; ++tk) {
        uint4 av0 = *(const uint4*)(ap0 + tk * 64);
        uint4 av1 = *(const uint4*)(ap1 + tk * 64);
        bf16x8 b0 = *(const bf16x8*)(Us + bo0 + tk * 64);
        bf16x8 b1 = *(const bf16x8*)(Us + bo1 + tk * 64);
        bf16x8 a0 = as_bf16x8(av0), a1 = as_bf16x8(av1);
        a00 = __builtin_amdgcn_mfma_f32_16x16x32_bf16(a0, b0, a00, 0, 0, 0);
        a01 = __builtin_amdgcn_mfma_f32_16x16x32_bf16(a0, b1, a01, 0, 0, 0);
        a10 = __builtin_amdgcn_mfma_f32_16x16x32_bf16(a1, b0, a10, 0, 0, 0);
        a11 = __builtin_amdgcn_mfma_f32_16x16x32_bf16(a1, b1, a11, 0, 0, 0);
      }
    }

    {
      int jb = n2 * 32 + (lane & 15);
      int rb = m2 * 32 + (lane >> 4) * 4;
      #pragma unroll
      for (int r = 0; r < 4; ++r) {
        zl[(rb + r) * 65 + jb]           = a00[r];
        zl[(rb + r) * 65 + jb + 16]      = a01[r];
        zl[(rb + 16 + r) * 65 + jb]      = a10[r];
        zl[(rb + 16 + r) * 65 + jb + 16] = a11[r];
      }
    }
    __syncthreads();

    {
      int jj0 = uq * 4;
      bool mk = (mb >> ub) & 1ull;
      unsigned long long pack = 0;
      float hv4[4];
      #pragma unroll
      for (int u = 0; u < 4; ++u) {
        int jj = jj0 + u;
        float zi = zl[ub * 65 + jj]      + get_bf_u2(xg[0], u);
        float zf = zl[ub * 65 + 16 + jj] + get_bf_u2(xg[1], u);
        float zg = zl[ub * 65 + 32 + jj] + get_bf_u2(xg[2], u);
        float zo = zl[ub * 65 + 48 + jj] + get_bf_u2(xg[3], u);
        float I = sigm(zi), F = sigm(zf), G = tanh_f(zg), O = sigm(zo);
        float cold = cb[ub * 16 + jj];
        float cn = F * cold + I * G;
        float hn = O * tanh_f(cn);
        if (!mk) { cn = cold; hn = ho[ub * 16 + jj]; }
        cb[ub * 16 + jj] = cn;
        ho[ub * 16 + jj] = hn;
        pack |= (unsigned long long)f2bf(hn) << (16 * u);
        hv4[u] = hn;
      }
      __hip_atomic_store(
        (unsigned long long*)((char*)hseq + (size_t)t * 131072 + ub * 2048 + (w * 16 + jj0) * 2),
        pack, __ATOMIC_RELAXED, __HIP_MEMORY_SCOPE_AGENT);
      if (t == TT - 1) {
        #pragma unroll
        for (int u = 0; u < 4; ++u) hfin[ub * 1024 + w * 16 + jj0 + u] = hv4[u];
      }
    }
    asm volatile("s_waitcnt vmcnt(0)" ::: "memory");
    __syncthreads();
    if (tid == 0)
      __hip_atomic_store(flags + (size_t)t * 64 + w, 1u, __ATOMIC_RELEASE, __HIP_MEMORY_SCOPE_AGENT);
  }
}

// ---------------- VAE head ----------------

__global__ void k_final(const float* __restrict__ hfin, const float* __restrict__ Wm,
                        const float* __restrict__ bm, const float* __restrict__ Wv,
                        const float* __restrict__ bv, const float* __restrict__ eps,
                        float* __restrict__ out) {
  int jb = blockIdx.x;
  int b = threadIdx.x & 63, u = threadIdx.x >> 6;
  int c0 = jb * 16 + u * 4;
  float am[4] = {0.f, 0.f, 0.f, 0.f};
  float av[4] = {0.f, 0.f, 0.f, 0.f};
  const float* hb = hfin + b * 1024;
  #pragma unroll 2
  for (int k = 0; k < 1024; ++k) {
    float hv = hb[k];
    float4 wm = *(const float4*)(Wm + (size_t)k * 1024 + c0);
    float4 wv = *(const float4*)(Wv + (size_t)k * 1024 + c0);
    am[0] += hv * wm.x; am[1] += hv * wm.y; am[2] += hv * wm.z; am[3] += hv * wm.w;
    av[0] += hv * wv.x; av[1] += hv * wv.y; av[2] += hv * wv.z; av[3] += hv * wv.w;
  }
  #pragma unroll
  for (int i = 0; i < 4; ++i) {
    int c = c0 + i;
    float mean = am[i] + bm[c];
    float lv = av[i] + bv[c];
    out[b * 1024 + c] = eps[b * 1024 + c] * __expf(0.5f * lv) + mean;
  }
}

// ---------------- launch ----------------

extern "C" void kernel_launch(void* const* d_in, const int* in_sizes, int n_in,
                              void* d_out, int out_size, void* d_ws, size_t ws_size,
                              hipStream_t stream) {
  const int*   tok = (const int*)d_in[0];
  const float* emb = (const float*)d_in[1];
  const float* W   = (const float*)d_in[2];
  const float* U   = (const float*)d_in[3];
  const float* bia = (const float*)d_in[4];
  const float* Wm  = (const float*)d_in[5];
  const float* bm  = (const float*)d_in[6];
  const float* Wv  = (const float*)d_in[7];
  const float* bv  = (const float*)d_in[8];
  const float* eps = (const float*)d_in[9];
  float* out = (float*)d_out;

  char* ws = (char*)d_ws;
  size_t off = 0;
  auto alloc = [&](size_t sz) { char* p = ws + off; off += (sz + 255) & ~(size_t)255; return p; };
  unsigned short* embb = (unsigned short*)alloc((size_t)VV * DD * 2);
  unsigned short* Wt   = (unsigned short*)alloc((size_t)FH * DD * 2);
  float*  bperm        = (float*)alloc((size_t)FH * 4);
  unsigned short* Uprep= (unsigned short*)alloc((size_t)64 * UBLK);
  unsigned short* xw   = (unsigned short*)alloc((size_t)BB * TT * FH * 2);
  unsigned short* hseq = (unsigned short*)alloc((size_t)TT * 131072);
  unsigned* flags      = (unsigned*)alloc((size_t)TT * 64 * 4);
  unsigned long long* mask64 = (unsigned long long*)alloc((size_t)TT * 8);
  float* hfin          = (float*)alloc((size_t)BB * HH * 4);
  (void)in_sizes; (void)n_in; (void)out_size; (void)ws_size;

  hipMemsetAsync(flags, 0, (size_t)TT * 64 * 4, stream);
  k_cast_emb<<<8000, 256, 0, stream>>>(emb, embb);
  k_prep_w<<<4096, 128, 0, stream>>>(W, bia, Wt, bperm);
  k_prep_u<<<4096, 128, 0, stream>>>(U, Uprep);
  k_mask<<<1, 256, 0, stream>>>(tok, mask64);
  k_gemm_xw<<<4096, 256, 0, stream>>>(tok, embb, Wt, bperm, xw);
  hipFuncSetAttribute((const void*)k_lstm, hipFuncAttributeMaxDynamicSharedMemorySize, LSTM_LDS);
  k_lstm<<<64, 256, LSTM_LDS, stream>>>(Uprep, xw, mask64, hseq, flags, hfin);
  k_final<<<64, 256, 0, stream>>>(hfin, Wm, bm, Wv, bv, eps, out);
}